// Round 1
// baseline (186.873 us; speedup 1.0000x reference)
//
#include <hip/hip_runtime.h>

// Problem constants (from reference setup_inputs)
constexpr int B  = 4;
constexpr int M  = 1088;
constexpr int HH = 32;
constexpr int D  = 128;
constexpr int F  = 128;
constexpr int C  = 512;

constexpr int SZ_YNUM = B * C * HH * D;   // 8388608
constexpr int SZ_YDEN = B * C * HH;       // 65536
constexpr int SZ_KVM  = B * M * HH * D;   // 17825792 (same for K, V, FK since D==F)
constexpr int SZ_H    = B * HH * F * D;   // 2097152
// S = B*HH*F = 16384

constexpr int OFF_YNUM = 0;
constexpr int OFF_YDEN = OFF_YNUM + SZ_YNUM;
constexpr int OFF_K    = OFF_YDEN + SZ_YDEN;
constexpr int OFF_V    = OFF_K + SZ_KVM;
constexpr int OFF_FK   = OFF_V + SZ_KVM;
constexpr int OFF_H    = OFF_FK + SZ_KVM;
constexpr int OFF_S    = OFF_H + SZ_H;

__device__ __forceinline__ void ring_params(const int* wp_p, const int* valid_p,
                                            int& wp, int& num_excess, int& pos) {
    wp = *wp_p;
    int valid = *valid_p;
    if (valid + C <= M) {
        num_excess = 0;
        pos = (wp + valid) % M;
    } else {
        num_excess = valid + C - M;
        pos = (wp + num_excess) % M;
    }
}

// ---------------------------------------------------------------------------
// Kernel: fused copy + ring write.  Works for K, V, FK (all (B,M,HH,128)).
// Element granularity: float4.  inner = HH*128/4 = 1024 float4 per (b,m).
// ---------------------------------------------------------------------------
__global__ __launch_bounds__(256) void ring_copy(const float4* __restrict__ src,
                                                 const float4* __restrict__ chunk,
                                                 float4* __restrict__ dst,
                                                 const int* __restrict__ wp_p,
                                                 const int* __restrict__ valid_p) {
    int wp, num_excess, pos;
    ring_params(wp_p, valid_p, wp, num_excess, pos);

    constexpr int INNER = HH * D / 4;  // 1024 (power of two)
    const int total = B * M * INNER;   // 4456448
    int idx = blockIdx.x * 256 + threadIdx.x;
    if (idx >= total) return;

    int inner = idx & (INNER - 1);
    int bm = idx >> 10;            // idx / INNER
    int m = bm % M;
    int b = bm / M;

    int off = m - pos;
    if (off < 0) off += M;
    if (off < C) {
        dst[idx] = chunk[(b * C + off) * INNER + inner];
    } else {
        dst[idx] = src[idx];
    }
}

// ---------------------------------------------------------------------------
// Kernel: H_new = H + sum_e FK[b,me,h,f] * V[b,me,h,d]; S_new = S + sum_e FK.
// Grid: B*HH*4 blocks.  Block computes a 32(f) x 128(d) tile of H[b,h].
// 256 threads: tf = tid>>5 (8 groups, 4 f each), td = tid&31 (4 d each, float4)
// ---------------------------------------------------------------------------
__global__ __launch_bounds__(256) void update_hs(const float* __restrict__ FKi,
                                                 const float* __restrict__ Vi,
                                                 const float* __restrict__ Hi,
                                                 const float* __restrict__ Si,
                                                 float* __restrict__ Ho,
                                                 float* __restrict__ So,
                                                 const int* __restrict__ wp_p,
                                                 const int* __restrict__ valid_p) {
    int wp, num_excess, pos;
    ring_params(wp_p, valid_p, wp, num_excess, pos);

    const int tid = threadIdx.x;
    const int fquart = blockIdx.x & 3;
    const int bh = blockIdx.x >> 2;
    const int h = bh & (HH - 1);
    const int b = bh >> 5;          // / HH
    const int fbase = fquart * 32;

    __shared__ float  fk_s[8][32];
    __shared__ float4 v_s[8][32];

    const int tf = tid >> 5;   // 0..7
    const int td = tid & 31;   // 0..31

    float acc[4][4];
#pragma unroll
    for (int i = 0; i < 4; ++i)
#pragma unroll
        for (int j = 0; j < 4; ++j) acc[i][j] = 0.f;
    float s_acc = 0.f;  // used by tid < 32 only

    for (int e0 = 0; e0 < num_excess; e0 += 8) {
        // Cooperative load of 8 e-rows (row = tf).
        {
            int e = e0 + tf;
            int me = wp + e;
            if (me >= M) me -= M;
            if (me >= M) me -= M;   // wp<M, e<C -> at most 2 subtractions
            const int rowbase = ((b * M + me) * HH + h);
            float fv = FKi[rowbase * F + fbase + td];
            float4 vv = *(const float4*)&Vi[rowbase * D + td * 4];
            if (e >= num_excess) {
                fv = 0.f;
                vv = make_float4(0.f, 0.f, 0.f, 0.f);
            }
            fk_s[tf][td] = fv;
            v_s[tf][td] = vv;
        }
        __syncthreads();
#pragma unroll
        for (int ee = 0; ee < 8; ++ee) {
            float4 vv = v_s[ee][td];
            float f0 = fk_s[ee][tf * 4 + 0];
            float f1 = fk_s[ee][tf * 4 + 1];
            float f2 = fk_s[ee][tf * 4 + 2];
            float f3 = fk_s[ee][tf * 4 + 3];
            acc[0][0] += f0 * vv.x; acc[0][1] += f0 * vv.y; acc[0][2] += f0 * vv.z; acc[0][3] += f0 * vv.w;
            acc[1][0] += f1 * vv.x; acc[1][1] += f1 * vv.y; acc[1][2] += f1 * vv.z; acc[1][3] += f1 * vv.w;
            acc[2][0] += f2 * vv.x; acc[2][1] += f2 * vv.y; acc[2][2] += f2 * vv.z; acc[2][3] += f2 * vv.w;
            acc[3][0] += f3 * vv.x; acc[3][1] += f3 * vv.y; acc[3][2] += f3 * vv.z; acc[3][3] += f3 * vv.w;
        }
        if (tid < 32) {
#pragma unroll
            for (int ee = 0; ee < 8; ++ee) s_acc += fk_s[ee][tid];
        }
        __syncthreads();
    }

    // Write H_new = H_old + acc
#pragma unroll
    for (int i = 0; i < 4; ++i) {
        int f = fbase + tf * 4 + i;
        int base = ((b * HH + h) * F + f) * D + td * 4;
        float4 hold = *(const float4*)&Hi[base];
        float4 r = make_float4(hold.x + acc[i][0], hold.y + acc[i][1],
                               hold.z + acc[i][2], hold.w + acc[i][3]);
        *(float4*)&Ho[base] = r;
    }
    if (tid < 32) {
        int f = fbase + tid;
        int si = (b * HH + h) * F + f;
        So[si] = Si[si] + s_acc;
    }
}

// ---------------------------------------------------------------------------
// Kernel: y_num[b,c,h,d] = sum_f fq[b,c,h,f] * H_new[b,h,f,d]
// Grid: B*HH*8 blocks. Block: 64(c) x 128(d) tile for one (b,h).
// 256 threads: tc = tid>>5 (8 groups, 8 c each), td = tid&31 (4 d, float4)
// ---------------------------------------------------------------------------
__global__ __launch_bounds__(256) void compute_y(const float* __restrict__ fq,
                                                 const float* __restrict__ Hn,
                                                 float* __restrict__ ynum) {
    const int tid = threadIdx.x;
    int t = blockIdx.x;
    const int ct = t & 7; t >>= 3;
    const int h = t & (HH - 1);
    const int b = t >> 5;
    const int c0 = ct * 64;

    __shared__ float  fq_s[64][8];
    __shared__ float4 h_s[8][32];

    const int tc = tid >> 5;  // 0..7
    const int td = tid & 31;  // 0..31

    float acc[8][4];
#pragma unroll
    for (int i = 0; i < 8; ++i)
#pragma unroll
        for (int j = 0; j < 4; ++j) acc[i][j] = 0.f;

    for (int f0 = 0; f0 < F; f0 += 8) {
        // fq tile: 64 rows x 8 f, 512 floats, each thread loads 2
#pragma unroll
        for (int r = 0; r < 2; ++r) {
            int idx = tid + r * 256;
            int cc = idx >> 3, ee = idx & 7;
            fq_s[cc][ee] = fq[((b * C + c0 + cc) * HH + h) * F + f0 + ee];
        }
        // H tile: 8 rows x 128 d as float4 (256 float4)
        {
            int row = tid >> 5, col4 = tid & 31;
            h_s[row][col4] = *(const float4*)&Hn[((b * HH + h) * F + f0 + row) * D + col4 * 4];
        }
        __syncthreads();
#pragma unroll
        for (int ee = 0; ee < 8; ++ee) {
            float4 hv = h_s[ee][td];
#pragma unroll
            for (int i = 0; i < 8; ++i) {
                float q = fq_s[tc * 8 + i][ee];
                acc[i][0] += q * hv.x; acc[i][1] += q * hv.y;
                acc[i][2] += q * hv.z; acc[i][3] += q * hv.w;
            }
        }
        __syncthreads();
    }

#pragma unroll
    for (int i = 0; i < 8; ++i) {
        int c = c0 + tc * 8 + i;
        int base = ((b * C + c) * HH + h) * D + td * 4;
        *(float4*)&ynum[base] = make_float4(acc[i][0], acc[i][1], acc[i][2], acc[i][3]);
    }
}

// ---------------------------------------------------------------------------
// Kernel: y_den[b,c,h] = sum_f fq[b,c,h,f] * S_new[b,h,f]
// One thread per (b,c,h); fq row is 128 consecutive floats.
// ---------------------------------------------------------------------------
__global__ __launch_bounds__(256) void compute_den(const float* __restrict__ fq,
                                                   const float* __restrict__ Sn,
                                                   float* __restrict__ yden) {
    int idx = blockIdx.x * 256 + threadIdx.x;  // ((b*C + c)*HH + h)
    if (idx >= B * C * HH) return;
    int h = idx & (HH - 1);
    int bc = idx >> 5;
    int b = bc >> 9;  // / C (C=512)

    const float4* q4 = (const float4*)&fq[idx * F];
    const float4* s4 = (const float4*)&Sn[(b * HH + h) * F];
    float acc = 0.f;
#pragma unroll
    for (int i = 0; i < F / 4; ++i) {
        float4 q = q4[i];
        float4 s = s4[i];
        acc += q.x * s.x + q.y * s.y + q.z * s.z + q.w * s.w;
    }
    yden[idx] = acc;
}

// ---------------------------------------------------------------------------
extern "C" void kernel_launch(void* const* d_in, const int* in_sizes, int n_in,
                              void* d_out, int out_size, void* d_ws, size_t ws_size,
                              hipStream_t stream) {
    const float* K   = (const float*)d_in[0];
    const float* V   = (const float*)d_in[1];
    const float* FK  = (const float*)d_in[2];
    const float* H   = (const float*)d_in[3];
    const float* S   = (const float*)d_in[4];
    const float* k_c = (const float*)d_in[5];
    const float* v_c = (const float*)d_in[6];
    const float* fk_c= (const float*)d_in[7];
    const float* fq  = (const float*)d_in[8];
    const int* wp    = (const int*)d_in[9];
    const int* valid = (const int*)d_in[10];

    float* out = (float*)d_out;
    float* o_ynum = out + OFF_YNUM;
    float* o_yden = out + OFF_YDEN;
    float* o_K    = out + OFF_K;
    float* o_V    = out + OFF_V;
    float* o_FK   = out + OFF_FK;
    float* o_H    = out + OFF_H;
    float* o_S    = out + OFF_S;

    // 1. State update (H_new, S_new into d_out)
    update_hs<<<B * HH * 4, 256, 0, stream>>>(FK, V, H, S, o_H, o_S, wp, valid);

    // 2. y_num = fq @ H_new ; y_den = fq . S_new  (read H_new/S_new from d_out)
    compute_y<<<B * HH * 8, 256, 0, stream>>>(fq, o_H, o_ynum);
    compute_den<<<(B * C * HH + 255) / 256, 256, 0, stream>>>(fq, o_S, o_yden);

    // 3. Ring-buffer copies (independent of the above)
    constexpr int COPY_BLOCKS = (SZ_KVM / 4 + 255) / 256;  // 17408
    ring_copy<<<COPY_BLOCKS, 256, 0, stream>>>((const float4*)K,  (const float4*)k_c,  (float4*)o_K,  wp, valid);
    ring_copy<<<COPY_BLOCKS, 256, 0, stream>>>((const float4*)V,  (const float4*)v_c,  (float4*)o_V,  wp, valid);
    ring_copy<<<COPY_BLOCKS, 256, 0, stream>>>((const float4*)FK, (const float4*)fk_c, (float4*)o_FK, wp, valid);
}

// Round 2
// 159.548 us; speedup vs baseline: 1.1713x; 1.1713x over previous
//
#include <hip/hip_runtime.h>

// Problem constants (from reference setup_inputs)
constexpr int B  = 4;
constexpr int M  = 1088;
constexpr int HH = 32;
constexpr int D  = 128;
constexpr int F  = 128;
constexpr int C  = 512;

constexpr int SZ_YNUM = B * C * HH * D;   // 8388608
constexpr int SZ_YDEN = B * C * HH;       // 65536
constexpr int SZ_KVM  = B * M * HH * D;   // 17825792 (same for K, V, FK since D==F)
constexpr int SZ_H    = B * HH * F * D;   // 2097152

constexpr int OFF_YNUM = 0;
constexpr int OFF_YDEN = OFF_YNUM + SZ_YNUM;
constexpr int OFF_K    = OFF_YDEN + SZ_YDEN;
constexpr int OFF_V    = OFF_K + SZ_KVM;
constexpr int OFF_FK   = OFF_V + SZ_KVM;
constexpr int OFF_H    = OFF_FK + SZ_KVM;
constexpr int OFF_S    = OFF_H + SZ_H;

__device__ __forceinline__ void ring_params(const int* wp_p, const int* valid_p,
                                            int& wp, int& num_excess, int& pos) {
    wp = *wp_p;
    int valid = *valid_p;
    if (valid + C <= M) {
        num_excess = 0;
        pos = (wp + valid) % M;
    } else {
        num_excess = valid + C - M;
        pos = (wp + num_excess) % M;
    }
}

// ---------------------------------------------------------------------------
// Fused ring copy for K, V, FK.  gridDim.z in {0,1,2} selects the tensor.
// ---------------------------------------------------------------------------
__global__ __launch_bounds__(256) void ring_copy3(
        const float4* __restrict__ K,  const float4* __restrict__ kc,  float4* __restrict__ oK,
        const float4* __restrict__ V,  const float4* __restrict__ vc,  float4* __restrict__ oV,
        const float4* __restrict__ FK, const float4* __restrict__ fkc, float4* __restrict__ oFK,
        const int* __restrict__ wp_p, const int* __restrict__ valid_p) {
    int wp, num_excess, pos;
    ring_params(wp_p, valid_p, wp, num_excess, pos);

    const int z = blockIdx.z;
    const float4* src = (z == 0) ? K  : (z == 1) ? V  : FK;
    const float4* chk = (z == 0) ? kc : (z == 1) ? vc : fkc;
    float4*       dst = (z == 0) ? oK : (z == 1) ? oV : oFK;

    constexpr int INNER = HH * D / 4;  // 1024 (power of two)
    int idx = blockIdx.x * 256 + threadIdx.x;   // grid sized exactly: B*M*INNER

    int inner = idx & (INNER - 1);
    int bm = idx >> 10;            // idx / INNER
    int m = bm % M;
    int b = bm / M;

    int off = m - pos;
    if (off < 0) off += M;
    if (off < C) {
        dst[idx] = chk[(b * C + off) * INNER + inner];
    } else {
        dst[idx] = src[idx];
    }
}

// ---------------------------------------------------------------------------
// H_new = H + sum_e FK[b,me,h,f] * V[b,me,h,d]; S_new = S + sum_e FK.
// Grid: B*HH*2 blocks.  Block computes a 64(f) x 128(d) tile of H[b,h].
// Register double-buffered staging (1 block/CU -> no TLP to hide latency).
// ---------------------------------------------------------------------------
constexpr int ESTEP = 16;

__global__ __launch_bounds__(256) void update_hs(const float* __restrict__ FKi,
                                                 const float* __restrict__ Vi,
                                                 const float* __restrict__ Hi,
                                                 const float* __restrict__ Si,
                                                 float* __restrict__ Ho,
                                                 float* __restrict__ So,
                                                 const int* __restrict__ wp_p,
                                                 const int* __restrict__ valid_p) {
    int wp, num_excess, pos;
    ring_params(wp_p, valid_p, wp, num_excess, pos);

    const int tid = threadIdx.x;
    const int fhalf = blockIdx.x & 1;
    const int bh = blockIdx.x >> 1;
    const int h = bh & (HH - 1);
    const int b = bh >> 5;
    const int fbase = fhalf * 64;

    __shared__ float  fk_s[ESTEP][64];   // 4 KB
    __shared__ float4 v_s[ESTEP][32];    // 8 KB
    __shared__ float  sred[4][64];       // 1 KB

    const int tf = tid >> 5;   // 0..7  (8 f-rows each)
    const int td = tid & 31;   // 0..31 (d quads)
    const int cq = tid & 63;   // fk column / s column
    const int qq = tid >> 6;   // quarter

    float acc[8][4];
#pragma unroll
    for (int i = 0; i < 8; ++i)
#pragma unroll
        for (int j = 0; j < 4; ++j) acc[i][j] = 0.f;
    float s_part = 0.f;

    float  fk_r[4];
    float4 v_r[2];

    auto load_tile = [&](int e0) {
#pragma unroll
        for (int j = 0; j < 4; ++j) {
            int e = e0 + qq + 4 * j;
            int me = wp + e;
            if (me >= M) me -= M;
            if (me >= M) me -= M;
            float v = 0.f;
            if (e < num_excess) v = FKi[((b * M + me) * HH + h) * F + fbase + cq];
            fk_r[j] = v;
        }
#pragma unroll
        for (int j = 0; j < 2; ++j) {
            int e = e0 + tf + 8 * j;
            int me = wp + e;
            if (me >= M) me -= M;
            if (me >= M) me -= M;
            float4 v = make_float4(0.f, 0.f, 0.f, 0.f);
            if (e < num_excess) v = *(const float4*)&Vi[((b * M + me) * HH + h) * D + td * 4];
            v_r[j] = v;
        }
    };
    auto store_tile = [&]() {
#pragma unroll
        for (int j = 0; j < 4; ++j) fk_s[qq + 4 * j][cq] = fk_r[j];
#pragma unroll
        for (int j = 0; j < 2; ++j) v_s[tf + 8 * j][td] = v_r[j];
    };

    if (num_excess > 0) {
        load_tile(0);
        store_tile();
        for (int e0 = 0; e0 < num_excess; e0 += ESTEP) {
            bool more = (e0 + ESTEP < num_excess);
            if (more) load_tile(e0 + ESTEP);   // loads in flight during compute
            __syncthreads();                   // staged tile visible
#pragma unroll
            for (int ee = 0; ee < ESTEP; ++ee) {
                float4 vv = v_s[ee][td];
#pragma unroll
                for (int i = 0; i < 8; ++i) {
                    float f = fk_s[ee][tf * 8 + i];
                    acc[i][0] += f * vv.x; acc[i][1] += f * vv.y;
                    acc[i][2] += f * vv.z; acc[i][3] += f * vv.w;
                }
            }
#pragma unroll
            for (int j = 0; j < 4; ++j) s_part += fk_s[qq * 4 + j][cq];
            __syncthreads();                   // all reads done
            if (more) store_tile();            // waits vmcnt, writes next tile
        }
    }

    // S_new
    sred[qq][cq] = s_part;
    __syncthreads();
    if (tid < 64) {
        int f = fbase + tid;
        int si = (b * HH + h) * F + f;
        So[si] = Si[si] + sred[0][tid] + sred[1][tid] + sred[2][tid] + sred[3][tid];
    }

    // H_new = H_old + acc
#pragma unroll
    for (int i = 0; i < 8; ++i) {
        int f = fbase + tf * 8 + i;
        int base = ((b * HH + h) * F + f) * D + td * 4;
        float4 hold = *(const float4*)&Hi[base];
        *(float4*)&Ho[base] = make_float4(hold.x + acc[i][0], hold.y + acc[i][1],
                                          hold.z + acc[i][2], hold.w + acc[i][3]);
    }
}

// ---------------------------------------------------------------------------
// y_num[b,c,h,d] = sum_f fq[b,c,h,f] * H_new[b,h,f,d]
// y_den[b,c,h]   = sum_f fq[b,c,h,f] * S_new[b,h,f]     (fused)
// Grid: B*HH*8 blocks. Block: 64(c) x 128(d) tile for one (b,h), f-step 32.
// ---------------------------------------------------------------------------
__global__ __launch_bounds__(256) void compute_y_den(const float* __restrict__ fq,
                                                     const float* __restrict__ Hn,
                                                     const float* __restrict__ Sn,
                                                     float* __restrict__ ynum,
                                                     float* __restrict__ yden) {
    const int tid = threadIdx.x;
    int t = blockIdx.x;
    const int ct = t & 7; t >>= 3;
    const int h = t & (HH - 1);
    const int b = t >> 5;
    const int c0 = ct * 64;

    __shared__ float  fq_s[32][65];   // [ee][c], padded (8320 B)
    __shared__ float4 h_s[32][32];    // [ee][d4]        (16 KB)
    __shared__ float  S_s[128];
    __shared__ float  den_s[64][4];

    const int tc = tid >> 5;  // 0..7 (8 c-rows each)
    const int td = tid & 31;  // 0..31 (d quads)
    const int cq = tid & 63;
    const int qq = tid >> 6;

    if (tid < 128) S_s[tid] = Sn[(b * HH + h) * F + tid];

    float acc[8][4];
#pragma unroll
    for (int i = 0; i < 8; ++i)
#pragma unroll
        for (int j = 0; j < 4; ++j) acc[i][j] = 0.f;
    float den_part = 0.f;

    for (int f0 = 0; f0 < F; f0 += 32) {
        // fq tile: 64 c x 32 f, transposed into fq_s[ee][c]; 8 loads/thread
#pragma unroll
        for (int r = 0; r < 8; ++r) {
            int idx = tid + r * 256;
            int cc = idx >> 5, ee = idx & 31;
            fq_s[ee][cc] = fq[((b * C + c0 + cc) * HH + h) * F + f0 + ee];
        }
        // H tile: 32 f x 128 d as float4; 4 loads/thread
#pragma unroll
        for (int r = 0; r < 4; ++r) {
            int idx = tid + r * 256;
            int row = idx >> 5, col = idx & 31;
            h_s[row][col] = *(const float4*)&Hn[((b * HH + h) * F + f0 + row) * D + col * 4];
        }
        __syncthreads();
#pragma unroll
        for (int ee = 0; ee < 32; ++ee) {
            float4 hv = h_s[ee][td];
#pragma unroll
            for (int i = 0; i < 8; ++i) {
                float q = fq_s[ee][tc * 8 + i];
                acc[i][0] += q * hv.x; acc[i][1] += q * hv.y;
                acc[i][2] += q * hv.z; acc[i][3] += q * hv.w;
            }
        }
        // den partials: thread (cq,qq) covers f = f0 + qq*8 .. +7 for row cq
#pragma unroll
        for (int j = 0; j < 8; ++j)
            den_part += fq_s[qq * 8 + j][cq] * S_s[f0 + qq * 8 + j];
        __syncthreads();
    }

    den_s[cq][qq] = den_part;
    __syncthreads();
    if (tid < 64)
        yden[(b * C + c0 + tid) * HH + h] =
            den_s[tid][0] + den_s[tid][1] + den_s[tid][2] + den_s[tid][3];

#pragma unroll
    for (int i = 0; i < 8; ++i) {
        int c = c0 + tc * 8 + i;
        int base = ((b * C + c) * HH + h) * D + td * 4;
        *(float4*)&ynum[base] = make_float4(acc[i][0], acc[i][1], acc[i][2], acc[i][3]);
    }
}

// ---------------------------------------------------------------------------
extern "C" void kernel_launch(void* const* d_in, const int* in_sizes, int n_in,
                              void* d_out, int out_size, void* d_ws, size_t ws_size,
                              hipStream_t stream) {
    const float* K   = (const float*)d_in[0];
    const float* V   = (const float*)d_in[1];
    const float* FK  = (const float*)d_in[2];
    const float* H   = (const float*)d_in[3];
    const float* S   = (const float*)d_in[4];
    const float* k_c = (const float*)d_in[5];
    const float* v_c = (const float*)d_in[6];
    const float* fk_c= (const float*)d_in[7];
    const float* fq  = (const float*)d_in[8];
    const int* wp    = (const int*)d_in[9];
    const int* valid = (const int*)d_in[10];

    float* out = (float*)d_out;
    float* o_ynum = out + OFF_YNUM;
    float* o_yden = out + OFF_YDEN;
    float* o_K    = out + OFF_K;
    float* o_V    = out + OFF_V;
    float* o_FK   = out + OFF_FK;
    float* o_H    = out + OFF_H;
    float* o_S    = out + OFF_S;

    // 1. State update (H_new, S_new into d_out)
    update_hs<<<B * HH * 2, 256, 0, stream>>>(FK, V, H, S, o_H, o_S, wp, valid);

    // 2. y_num = fq @ H_new ; y_den = fq . S_new (fused)
    compute_y_den<<<B * HH * 8, 256, 0, stream>>>(fq, o_H, o_S, o_ynum, o_yden);

    // 3. Ring-buffer copies (one kernel, z selects tensor)
    constexpr int COPY_BLOCKS = SZ_KVM / 4 / 256;  // 17408, exact
    ring_copy3<<<dim3(COPY_BLOCKS, 1, 3), 256, 0, stream>>>(
        (const float4*)K,  (const float4*)k_c,  (float4*)o_K,
        (const float4*)V,  (const float4*)v_c,  (float4*)o_V,
        (const float4*)FK, (const float4*)fk_c, (float4*)o_FK,
        wp, valid);
}

// Round 3
// 134.345 us; speedup vs baseline: 1.3910x; 1.1876x over previous
//
#include <hip/hip_runtime.h>

// Problem constants (from reference setup_inputs)
constexpr int B  = 4;
constexpr int M  = 1088;
constexpr int HH = 32;
constexpr int D  = 128;
constexpr int F  = 128;
constexpr int C  = 512;

constexpr int SZ_YNUM = B * C * HH * D;   // 8388608
constexpr int SZ_YDEN = B * C * HH;       // 65536
constexpr int SZ_KVM  = B * M * HH * D;   // 17825792 (same for K, V, FK since D==F)
constexpr int SZ_H    = B * HH * F * D;   // 2097152

constexpr int OFF_YNUM = 0;
constexpr int OFF_YDEN = OFF_YNUM + SZ_YNUM;
constexpr int OFF_K    = OFF_YDEN + SZ_YDEN;
constexpr int OFF_V    = OFF_K + SZ_KVM;
constexpr int OFF_FK   = OFF_V + SZ_KVM;
constexpr int OFF_H    = OFF_FK + SZ_KVM;
constexpr int OFF_S    = OFF_H + SZ_H;

constexpr int COPY_BLOCKS = SZ_KVM / 4 / 256;  // 17408 (exact)
constexpr int HS_BLOCKS   = B * HH * 2;        // 256
constexpr int Y_BLOCKS    = B * HH * 8;        // 1024

__device__ __forceinline__ void ring_params(const int* wp_p, const int* valid_p,
                                            int& wp, int& num_excess, int& pos) {
    wp = *wp_p;
    int valid = *valid_p;
    if (valid + C <= M) {
        num_excess = 0;
        pos = (wp + valid) % M;
    } else {
        num_excess = valid + C - M;
        pos = (wp + num_excess) % M;
    }
}

// ---------------------------------------------------------------------------
// One copy block = 256 float4 of one (B,M,HH,128) tensor, ring-overwritten.
// ---------------------------------------------------------------------------
__device__ __forceinline__ void ring_copy_block(int cb, int tid,
                                                const float4* __restrict__ src,
                                                const float4* __restrict__ chk,
                                                float4* __restrict__ dst,
                                                int pos) {
    constexpr int INNER = HH * D / 4;  // 1024 (power of two)
    int idx = cb * 256 + tid;

    int inner = idx & (INNER - 1);
    int bm = idx >> 10;
    int m = bm % M;
    int b = bm / M;

    int off = m - pos;
    if (off < 0) off += M;
    if (off < C) {
        dst[idx] = chk[(b * C + off) * INNER + inner];
    } else {
        dst[idx] = src[idx];
    }
}

// ---------------------------------------------------------------------------
// update_hs body: block bx in [0,256). 64(f) x 128(d) tile of H[b,h].
// Register double-buffered LDS staging.
// ---------------------------------------------------------------------------
constexpr int ESTEP = 16;

__device__ void update_hs_body(int bx,
                               const float* __restrict__ FKi,
                               const float* __restrict__ Vi,
                               const float* __restrict__ Hi,
                               const float* __restrict__ Si,
                               float* __restrict__ Ho,
                               float* __restrict__ So,
                               int wp, int num_excess) {
    const int tid = threadIdx.x;
    const int fhalf = bx & 1;
    const int bh = bx >> 1;
    const int h = bh & (HH - 1);
    const int b = bh >> 5;
    const int fbase = fhalf * 64;

    __shared__ float  fk_s[ESTEP][64];   // 4 KB
    __shared__ float4 v_s[ESTEP][32];    // 8 KB
    __shared__ float  sred[4][64];       // 1 KB

    const int tf = tid >> 5;   // 0..7  (8 f-rows each)
    const int td = tid & 31;   // 0..31 (d quads)
    const int cq = tid & 63;   // fk column / s column
    const int qq = tid >> 6;   // quarter

    float acc[8][4];
#pragma unroll
    for (int i = 0; i < 8; ++i)
#pragma unroll
        for (int j = 0; j < 4; ++j) acc[i][j] = 0.f;
    float s_part = 0.f;

    float  fk_r[4];
    float4 v_r[2];

    auto load_tile = [&](int e0) {
#pragma unroll
        for (int j = 0; j < 4; ++j) {
            int e = e0 + qq + 4 * j;
            int me = wp + e;
            if (me >= M) me -= M;
            if (me >= M) me -= M;
            float v = 0.f;
            if (e < num_excess) v = FKi[((b * M + me) * HH + h) * F + fbase + cq];
            fk_r[j] = v;
        }
#pragma unroll
        for (int j = 0; j < 2; ++j) {
            int e = e0 + tf + 8 * j;
            int me = wp + e;
            if (me >= M) me -= M;
            if (me >= M) me -= M;
            float4 v = make_float4(0.f, 0.f, 0.f, 0.f);
            if (e < num_excess) v = *(const float4*)&Vi[((b * M + me) * HH + h) * D + td * 4];
            v_r[j] = v;
        }
    };
    auto store_tile = [&]() {
#pragma unroll
        for (int j = 0; j < 4; ++j) fk_s[qq + 4 * j][cq] = fk_r[j];
#pragma unroll
        for (int j = 0; j < 2; ++j) v_s[tf + 8 * j][td] = v_r[j];
    };

    if (num_excess > 0) {
        load_tile(0);
        store_tile();
        for (int e0 = 0; e0 < num_excess; e0 += ESTEP) {
            bool more = (e0 + ESTEP < num_excess);
            if (more) load_tile(e0 + ESTEP);   // loads in flight during compute
            __syncthreads();                   // staged tile visible
#pragma unroll
            for (int ee = 0; ee < ESTEP; ++ee) {
                float4 vv = v_s[ee][td];
#pragma unroll
                for (int i = 0; i < 8; ++i) {
                    float f = fk_s[ee][tf * 8 + i];
                    acc[i][0] += f * vv.x; acc[i][1] += f * vv.y;
                    acc[i][2] += f * vv.z; acc[i][3] += f * vv.w;
                }
            }
#pragma unroll
            for (int j = 0; j < 4; ++j) s_part += fk_s[qq * 4 + j][cq];
            __syncthreads();                   // all reads done
            if (more) store_tile();            // waits vmcnt, writes next tile
        }
    }

    // S_new
    sred[qq][cq] = s_part;
    __syncthreads();
    if (tid < 64) {
        int f = fbase + tid;
        int si = (b * HH + h) * F + f;
        So[si] = Si[si] + sred[0][tid] + sred[1][tid] + sred[2][tid] + sred[3][tid];
    }

    // H_new = H_old + acc
#pragma unroll
    for (int i = 0; i < 8; ++i) {
        int f = fbase + tf * 8 + i;
        int base = ((b * HH + h) * F + f) * D + td * 4;
        float4 hold = *(const float4*)&Hi[base];
        *(float4*)&Ho[base] = make_float4(hold.x + acc[i][0], hold.y + acc[i][1],
                                          hold.z + acc[i][2], hold.w + acc[i][3]);
    }
}

// ---------------------------------------------------------------------------
// compute_y_den body: block bx in [0,1024). 64(c) x 128(d) tile, f-step 32.
// ---------------------------------------------------------------------------
__device__ void compute_y_den_body(int bx,
                                   const float* __restrict__ fq,
                                   const float* __restrict__ Hn,
                                   const float* __restrict__ Sn,
                                   float* __restrict__ ynum,
                                   float* __restrict__ yden) {
    const int tid = threadIdx.x;
    int t = bx;
    const int ct = t & 7; t >>= 3;
    const int h = t & (HH - 1);
    const int b = t >> 5;
    const int c0 = ct * 64;

    __shared__ float  fq_s[32][65];   // [ee][c], padded
    __shared__ float4 h_s[32][32];    // [ee][d4]
    __shared__ float  S_s[128];
    __shared__ float  den_s[64][4];

    const int tc = tid >> 5;  // 0..7 (8 c-rows each)
    const int td = tid & 31;  // 0..31 (d quads)
    const int cq = tid & 63;
    const int qq = tid >> 6;

    if (tid < 128) S_s[tid] = Sn[(b * HH + h) * F + tid];

    float acc[8][4];
#pragma unroll
    for (int i = 0; i < 8; ++i)
#pragma unroll
        for (int j = 0; j < 4; ++j) acc[i][j] = 0.f;
    float den_part = 0.f;

    for (int f0 = 0; f0 < F; f0 += 32) {
#pragma unroll
        for (int r = 0; r < 8; ++r) {
            int idx = tid + r * 256;
            int cc = idx >> 5, ee = idx & 31;
            fq_s[ee][cc] = fq[((b * C + c0 + cc) * HH + h) * F + f0 + ee];
        }
#pragma unroll
        for (int r = 0; r < 4; ++r) {
            int idx = tid + r * 256;
            int row = idx >> 5, col = idx & 31;
            h_s[row][col] = *(const float4*)&Hn[((b * HH + h) * F + f0 + row) * D + col * 4];
        }
        __syncthreads();
#pragma unroll
        for (int ee = 0; ee < 32; ++ee) {
            float4 hv = h_s[ee][td];
#pragma unroll
            for (int i = 0; i < 8; ++i) {
                float q = fq_s[ee][tc * 8 + i];
                acc[i][0] += q * hv.x; acc[i][1] += q * hv.y;
                acc[i][2] += q * hv.z; acc[i][3] += q * hv.w;
            }
        }
#pragma unroll
        for (int j = 0; j < 8; ++j)
            den_part += fq_s[qq * 8 + j][cq] * S_s[f0 + qq * 8 + j];
        __syncthreads();
    }

    den_s[cq][qq] = den_part;
    __syncthreads();
    if (tid < 64)
        yden[(b * C + c0 + tid) * HH + h] =
            den_s[tid][0] + den_s[tid][1] + den_s[tid][2] + den_s[tid][3];

#pragma unroll
    for (int i = 0; i < 8; ++i) {
        int c = c0 + tc * 8 + i;
        int base = ((b * C + c) * HH + h) * D + td * 4;
        *(float4*)&ynum[base] = make_float4(acc[i][0], acc[i][1], acc[i][2], acc[i][3]);
    }
}

// ---------------------------------------------------------------------------
// Kernel 1: update_hs (blocks 0..255) + K copy + V copy (co-resident for BW).
// ---------------------------------------------------------------------------
__global__ __launch_bounds__(256) void fused_hs_kv(
        const float* __restrict__ FKi, const float* __restrict__ Vi,
        const float* __restrict__ Hi,  const float* __restrict__ Si,
        float* __restrict__ Ho,        float* __restrict__ So,
        const float4* __restrict__ K,  const float4* __restrict__ kc, float4* __restrict__ oK,
        const float4* __restrict__ V4, const float4* __restrict__ vc, float4* __restrict__ oV,
        const int* __restrict__ wp_p,  const int* __restrict__ valid_p) {
    int wp, num_excess, pos;
    ring_params(wp_p, valid_p, wp, num_excess, pos);

    int bx = blockIdx.x;
    if (bx < HS_BLOCKS) {
        update_hs_body(bx, FKi, Vi, Hi, Si, Ho, So, wp, num_excess);
        return;
    }
    bx -= HS_BLOCKS;
    if (bx < COPY_BLOCKS) {
        ring_copy_block(bx, threadIdx.x, K, kc, oK, pos);
        return;
    }
    bx -= COPY_BLOCKS;
    ring_copy_block(bx, threadIdx.x, V4, vc, oV, pos);
}

// ---------------------------------------------------------------------------
// Kernel 2: compute_y_den (blocks 0..1023) + FK copy.
// ---------------------------------------------------------------------------
__global__ __launch_bounds__(256) void fused_y_fk(
        const float* __restrict__ fq, const float* __restrict__ Hn,
        const float* __restrict__ Sn,
        float* __restrict__ ynum,     float* __restrict__ yden,
        const float4* __restrict__ FK, const float4* __restrict__ fkc,
        float4* __restrict__ oFK,
        const int* __restrict__ wp_p,  const int* __restrict__ valid_p) {
    int wp, num_excess, pos;
    ring_params(wp_p, valid_p, wp, num_excess, pos);

    int bx = blockIdx.x;
    if (bx < Y_BLOCKS) {
        compute_y_den_body(bx, fq, Hn, Sn, ynum, yden);
        return;
    }
    bx -= Y_BLOCKS;
    ring_copy_block(bx, threadIdx.x, FK, fkc, oFK, pos);
}

// ---------------------------------------------------------------------------
extern "C" void kernel_launch(void* const* d_in, const int* in_sizes, int n_in,
                              void* d_out, int out_size, void* d_ws, size_t ws_size,
                              hipStream_t stream) {
    const float* K   = (const float*)d_in[0];
    const float* V   = (const float*)d_in[1];
    const float* FK  = (const float*)d_in[2];
    const float* H   = (const float*)d_in[3];
    const float* S   = (const float*)d_in[4];
    const float* k_c = (const float*)d_in[5];
    const float* v_c = (const float*)d_in[6];
    const float* fk_c= (const float*)d_in[7];
    const float* fq  = (const float*)d_in[8];
    const int* wp    = (const int*)d_in[9];
    const int* valid = (const int*)d_in[10];

    float* out = (float*)d_out;
    float* o_ynum = out + OFF_YNUM;
    float* o_yden = out + OFF_YDEN;
    float* o_K    = out + OFF_K;
    float* o_V    = out + OFF_V;
    float* o_FK   = out + OFF_FK;
    float* o_H    = out + OFF_H;
    float* o_S    = out + OFF_S;

    // Kernel 1: H/S update overlapped with K,V ring copies.
    fused_hs_kv<<<HS_BLOCKS + 2 * COPY_BLOCKS, 256, 0, stream>>>(
        FK, V, H, S, o_H, o_S,
        (const float4*)K, (const float4*)k_c, (float4*)o_K,
        (const float4*)V, (const float4*)v_c, (float4*)o_V,
        wp, valid);

    // Kernel 2: y_num/y_den (reads H_new, S_new) overlapped with FK ring copy.
    fused_y_fk<<<Y_BLOCKS + COPY_BLOCKS, 256, 0, stream>>>(
        fq, o_H, o_S, o_ynum, o_yden,
        (const float4*)FK, (const float4*)fk_c, (float4*)o_FK,
        wp, valid);
}

// Round 4
// 127.618 us; speedup vs baseline: 1.4643x; 1.0527x over previous
//
#include <hip/hip_runtime.h>

// Problem constants (from reference setup_inputs)
constexpr int B  = 4;
constexpr int M  = 1088;
constexpr int HH = 32;
constexpr int D  = 128;
constexpr int F  = 128;
constexpr int C  = 512;

constexpr int SZ_YNUM = B * C * HH * D;   // 8388608
constexpr int SZ_YDEN = B * C * HH;       // 65536
constexpr int SZ_KVM  = B * M * HH * D;   // 17825792 (same for K, V, FK since D==F)
constexpr int SZ_H    = B * HH * F * D;   // 2097152

constexpr int OFF_YNUM = 0;
constexpr int OFF_YDEN = OFF_YNUM + SZ_YNUM;
constexpr int OFF_K    = OFF_YDEN + SZ_YDEN;
constexpr int OFF_V    = OFF_K + SZ_KVM;
constexpr int OFF_FK   = OFF_V + SZ_KVM;
constexpr int OFF_H    = OFF_FK + SZ_KVM;
constexpr int OFF_S    = OFF_H + SZ_H;

constexpr int INNER4      = HH * D / 4;    // 1024 float4 per (b,m) row
constexpr int ROWS_PER_CB = 4;             // rows copied per block (64 KB)
constexpr int COPY_BLOCKS = B * M / ROWS_PER_CB;  // 1088 (exact)
constexpr int HS_BLOCKS   = B * HH * 2;    // 256
constexpr int Y_BLOCKS    = B * HH * 8;    // 1024

__device__ __forceinline__ void ring_params(const int* wp_p, const int* valid_p,
                                            int& wp, int& num_excess, int& pos) {
    wp = *wp_p;
    int valid = *valid_p;
    if (valid + C <= M) {
        num_excess = 0;
        pos = (wp + valid) % M;
    } else {
        num_excess = valid + C - M;
        pos = (wp + num_excess) % M;
    }
}

// ---------------------------------------------------------------------------
// One copy block = ROWS_PER_CB (b,m)-rows (64 KB) of one (B,M,HH,128) tensor.
// Ring decision is wave-uniform per row; 16 float4 per thread in flight.
// ---------------------------------------------------------------------------
__device__ __forceinline__ void ring_copy_block(int cb, int tid,
                                                const float4* __restrict__ src,
                                                const float4* __restrict__ chk,
                                                float4* __restrict__ dst,
                                                int pos) {
    int bm0 = cb * ROWS_PER_CB;
#pragma unroll
    for (int r = 0; r < ROWS_PER_CB; ++r) {
        int bm = bm0 + r;
        int m = bm % M;
        int b = bm / M;
        int off = m - pos;
        if (off < 0) off += M;
        const float4* s = (off < C) ? &chk[(b * C + off) * INNER4]
                                    : &src[bm * INNER4];
        float4* d = &dst[bm * INNER4];
#pragma unroll
        for (int k = 0; k < INNER4 / 256; ++k)   // 4 segments of 256 float4
            d[k * 256 + tid] = s[k * 256 + tid];
    }
}

// ---------------------------------------------------------------------------
// update_hs body: block bx in [0,256). 64(f) x 128(d) tile of H[b,h].
// Register double-buffered LDS staging.
// ---------------------------------------------------------------------------
constexpr int ESTEP = 16;

__device__ void update_hs_body(int bx,
                               const float* __restrict__ FKi,
                               const float* __restrict__ Vi,
                               const float* __restrict__ Hi,
                               const float* __restrict__ Si,
                               float* __restrict__ Ho,
                               float* __restrict__ So,
                               int wp, int num_excess) {
    const int tid = threadIdx.x;
    const int fhalf = bx & 1;
    const int bh = bx >> 1;
    const int h = bh & (HH - 1);
    const int b = bh >> 5;
    const int fbase = fhalf * 64;

    __shared__ float  fk_s[ESTEP][64];   // 4 KB
    __shared__ float4 v_s[ESTEP][32];    // 8 KB
    __shared__ float  sred[4][64];       // 1 KB

    const int tf = tid >> 5;   // 0..7  (8 f-rows each)
    const int td = tid & 31;   // 0..31 (d quads)
    const int cq = tid & 63;   // fk column / s column
    const int qq = tid >> 6;   // quarter

    float acc[8][4];
#pragma unroll
    for (int i = 0; i < 8; ++i)
#pragma unroll
        for (int j = 0; j < 4; ++j) acc[i][j] = 0.f;
    float s_part = 0.f;

    float  fk_r[4];
    float4 v_r[2];

    auto load_tile = [&](int e0) {
#pragma unroll
        for (int j = 0; j < 4; ++j) {
            int e = e0 + qq + 4 * j;
            int me = wp + e;
            if (me >= M) me -= M;
            if (me >= M) me -= M;
            float v = 0.f;
            if (e < num_excess) v = FKi[((b * M + me) * HH + h) * F + fbase + cq];
            fk_r[j] = v;
        }
#pragma unroll
        for (int j = 0; j < 2; ++j) {
            int e = e0 + tf + 8 * j;
            int me = wp + e;
            if (me >= M) me -= M;
            if (me >= M) me -= M;
            float4 v = make_float4(0.f, 0.f, 0.f, 0.f);
            if (e < num_excess) v = *(const float4*)&Vi[((b * M + me) * HH + h) * D + td * 4];
            v_r[j] = v;
        }
    };
    auto store_tile = [&]() {
#pragma unroll
        for (int j = 0; j < 4; ++j) fk_s[qq + 4 * j][cq] = fk_r[j];
#pragma unroll
        for (int j = 0; j < 2; ++j) v_s[tf + 8 * j][td] = v_r[j];
    };

    if (num_excess > 0) {
        load_tile(0);
        store_tile();
        for (int e0 = 0; e0 < num_excess; e0 += ESTEP) {
            bool more = (e0 + ESTEP < num_excess);
            if (more) load_tile(e0 + ESTEP);   // loads in flight during compute
            __syncthreads();                   // staged tile visible
#pragma unroll
            for (int ee = 0; ee < ESTEP; ++ee) {
                float4 vv = v_s[ee][td];
#pragma unroll
                for (int i = 0; i < 8; ++i) {
                    float f = fk_s[ee][tf * 8 + i];
                    acc[i][0] += f * vv.x; acc[i][1] += f * vv.y;
                    acc[i][2] += f * vv.z; acc[i][3] += f * vv.w;
                }
            }
#pragma unroll
            for (int j = 0; j < 4; ++j) s_part += fk_s[qq * 4 + j][cq];
            __syncthreads();                   // all reads done
            if (more) store_tile();            // waits vmcnt, writes next tile
        }
    }

    // S_new
    sred[qq][cq] = s_part;
    __syncthreads();
    if (tid < 64) {
        int f = fbase + tid;
        int si = (b * HH + h) * F + f;
        So[si] = Si[si] + sred[0][tid] + sred[1][tid] + sred[2][tid] + sred[3][tid];
    }

    // H_new = H_old + acc
#pragma unroll
    for (int i = 0; i < 8; ++i) {
        int f = fbase + tf * 8 + i;
        int base = ((b * HH + h) * F + f) * D + td * 4;
        float4 hold = *(const float4*)&Hi[base];
        *(float4*)&Ho[base] = make_float4(hold.x + acc[i][0], hold.y + acc[i][1],
                                          hold.z + acc[i][2], hold.w + acc[i][3]);
    }
}

// ---------------------------------------------------------------------------
// compute_y_den body: block bx in [0,1024). 64(c) x 128(d) tile, f-step 32.
// ---------------------------------------------------------------------------
__device__ void compute_y_den_body(int bx,
                                   const float* __restrict__ fq,
                                   const float* __restrict__ Hn,
                                   const float* __restrict__ Sn,
                                   float* __restrict__ ynum,
                                   float* __restrict__ yden) {
    const int tid = threadIdx.x;
    int t = bx;
    const int ct = t & 7; t >>= 3;
    const int h = t & (HH - 1);
    const int b = t >> 5;
    const int c0 = ct * 64;

    __shared__ float  fq_s[32][65];   // [ee][c], padded
    __shared__ float4 h_s[32][32];    // [ee][d4]
    __shared__ float  S_s[128];
    __shared__ float  den_s[64][4];

    const int tc = tid >> 5;  // 0..7 (8 c-rows each)
    const int td = tid & 31;  // 0..31 (d quads)
    const int cq = tid & 63;
    const int qq = tid >> 6;

    if (tid < 128) S_s[tid] = Sn[(b * HH + h) * F + tid];

    float acc[8][4];
#pragma unroll
    for (int i = 0; i < 8; ++i)
#pragma unroll
        for (int j = 0; j < 4; ++j) acc[i][j] = 0.f;
    float den_part = 0.f;

    for (int f0 = 0; f0 < F; f0 += 32) {
#pragma unroll
        for (int r = 0; r < 8; ++r) {
            int idx = tid + r * 256;
            int cc = idx >> 5, ee = idx & 31;
            fq_s[ee][cc] = fq[((b * C + c0 + cc) * HH + h) * F + f0 + ee];
        }
#pragma unroll
        for (int r = 0; r < 4; ++r) {
            int idx = tid + r * 256;
            int row = idx >> 5, col = idx & 31;
            h_s[row][col] = *(const float4*)&Hn[((b * HH + h) * F + f0 + row) * D + col * 4];
        }
        __syncthreads();
#pragma unroll
        for (int ee = 0; ee < 32; ++ee) {
            float4 hv = h_s[ee][td];
#pragma unroll
            for (int i = 0; i < 8; ++i) {
                float q = fq_s[ee][tc * 8 + i];
                acc[i][0] += q * hv.x; acc[i][1] += q * hv.y;
                acc[i][2] += q * hv.z; acc[i][3] += q * hv.w;
            }
        }
#pragma unroll
        for (int j = 0; j < 8; ++j)
            den_part += fq_s[qq * 8 + j][cq] * S_s[f0 + qq * 8 + j];
        __syncthreads();
    }

    den_s[cq][qq] = den_part;
    __syncthreads();
    if (tid < 64)
        yden[(b * C + c0 + tid) * HH + h] =
            den_s[tid][0] + den_s[tid][1] + den_s[tid][2] + den_s[tid][3];

#pragma unroll
    for (int i = 0; i < 8; ++i) {
        int c = c0 + tc * 8 + i;
        int base = ((b * C + c) * HH + h) * D + td * 4;
        *(float4*)&ynum[base] = make_float4(acc[i][0], acc[i][1], acc[i][2], acc[i][3]);
    }
}

// ---------------------------------------------------------------------------
// Kernel 1: update_hs (blocks 0..255) + V copy + FK copy.
// hs reads the V/FK slice rows, which the copies re-read -> L3 sharing.
// ---------------------------------------------------------------------------
__global__ __launch_bounds__(256) void fused_hs_vfk(
        const float* __restrict__ FKi, const float* __restrict__ Vi,
        const float* __restrict__ Hi,  const float* __restrict__ Si,
        float* __restrict__ Ho,        float* __restrict__ So,
        const float4* __restrict__ V4, const float4* __restrict__ vc, float4* __restrict__ oV,
        const float4* __restrict__ FK4,const float4* __restrict__ fkc,float4* __restrict__ oFK,
        const int* __restrict__ wp_p,  const int* __restrict__ valid_p) {
    int wp, num_excess, pos;
    ring_params(wp_p, valid_p, wp, num_excess, pos);

    int bx = blockIdx.x;
    if (bx < HS_BLOCKS) {
        update_hs_body(bx, FKi, Vi, Hi, Si, Ho, So, wp, num_excess);
        return;
    }
    bx -= HS_BLOCKS;
    if (bx < COPY_BLOCKS) {
        ring_copy_block(bx, threadIdx.x, V4, vc, oV, pos);
        return;
    }
    bx -= COPY_BLOCKS;
    ring_copy_block(bx, threadIdx.x, FK4, fkc, oFK, pos);
}

// ---------------------------------------------------------------------------
// Kernel 2: compute_y_den (blocks 0..1023) + K copy.
// ---------------------------------------------------------------------------
__global__ __launch_bounds__(256) void fused_y_k(
        const float* __restrict__ fq, const float* __restrict__ Hn,
        const float* __restrict__ Sn,
        float* __restrict__ ynum,     float* __restrict__ yden,
        const float4* __restrict__ K4, const float4* __restrict__ kc,
        float4* __restrict__ oK,
        const int* __restrict__ wp_p,  const int* __restrict__ valid_p) {
    int wp, num_excess, pos;
    ring_params(wp_p, valid_p, wp, num_excess, pos);

    int bx = blockIdx.x;
    if (bx < Y_BLOCKS) {
        compute_y_den_body(bx, fq, Hn, Sn, ynum, yden);
        return;
    }
    bx -= Y_BLOCKS;
    ring_copy_block(bx, threadIdx.x, K4, kc, oK, pos);
}

// ---------------------------------------------------------------------------
extern "C" void kernel_launch(void* const* d_in, const int* in_sizes, int n_in,
                              void* d_out, int out_size, void* d_ws, size_t ws_size,
                              hipStream_t stream) {
    const float* K   = (const float*)d_in[0];
    const float* V   = (const float*)d_in[1];
    const float* FK  = (const float*)d_in[2];
    const float* H   = (const float*)d_in[3];
    const float* S   = (const float*)d_in[4];
    const float* k_c = (const float*)d_in[5];
    const float* v_c = (const float*)d_in[6];
    const float* fk_c= (const float*)d_in[7];
    const float* fq  = (const float*)d_in[8];
    const int* wp    = (const int*)d_in[9];
    const int* valid = (const int*)d_in[10];

    float* out = (float*)d_out;
    float* o_ynum = out + OFF_YNUM;
    float* o_yden = out + OFF_YDEN;
    float* o_K    = out + OFF_K;
    float* o_V    = out + OFF_V;
    float* o_FK   = out + OFF_FK;
    float* o_H    = out + OFF_H;
    float* o_S    = out + OFF_S;

    // Kernel 1: H/S update overlapped with V, FK ring copies (L3 slice reuse).
    fused_hs_vfk<<<HS_BLOCKS + 2 * COPY_BLOCKS, 256, 0, stream>>>(
        FK, V, H, S, o_H, o_S,
        (const float4*)V,  (const float4*)v_c,  (float4*)o_V,
        (const float4*)FK, (const float4*)fk_c, (float4*)o_FK,
        wp, valid);

    // Kernel 2: y_num/y_den (reads H_new, S_new) overlapped with K ring copy.
    fused_y_k<<<Y_BLOCKS + COPY_BLOCKS, 256, 0, stream>>>(
        fq, o_H, o_S, o_ynum, o_yden,
        (const float4*)K, (const float4*)k_c, (float4*)o_K,
        wp, valid);
}